// Round 8
// baseline (551.331 us; speedup 1.0000x reference)
//
#include <hip/hip_runtime.h>

#define D_FEAT 128
#define CAP 32
#define S1CAP (1 << 16)
#define S2CAP (1 << 16)
#define LOGB 7
#define LOCB 128
#define BCAP 2560
#define CHUNK 4096
#define NBUK_MAX 1024
#define BPAD 8
#define USPAN 8
#define BUILD_BLOCKS 1280

typedef short bf16x8 __attribute__((ext_vector_type(8)));
typedef float f32x4 __attribute__((ext_vector_type(4)));

__device__ __forceinline__ unsigned short f2bf(float f) {
    unsigned u = __builtin_bit_cast(unsigned, f);
    u += 0x7FFF + ((u >> 16) & 1);   // round-to-nearest-even
    return (unsigned short)(u >> 16);
}

// ws int layout: [flag:64][cursor:N][s1cnt:64][spill1:2*S1CAP][s2cnt:64]
// [spill2:2*S2CAP][bincnt:NBUK_MAX*BPAD][q:64 (binq,xbq,fillq,done)]
// [bins:NBUK*BCAP][adj:N*CAP] then Wc[128*256] bf16, xb[N*64] uint (bf16x2)

// ---------------- K0: tiny prep: detect i64 + zero counters/queues ----------
__global__ __launch_bounds__(256) void tprep_kernel(
    const int* __restrict__ ei, int* __restrict__ flag, int* __restrict__ s1cnt,
    int* __restrict__ s2cnt, int* __restrict__ bincnt, int* __restrict__ q) {
    const int b = blockIdx.x;
    const int t = threadIdx.x;
    for (int i = b * 256 + t; i < NBUK_MAX * BPAD; i += 8 * 256) bincnt[i] = 0;
    if (b == 0) {
        if (t < 64) q[t] = 0;
        __shared__ int nzs[4];
        int nz = 0;
        for (int i = t; i < 4096; i += 256) nz |= (ei[2 * i + 1] != 0);
        unsigned long long bal = __ballot(nz);
        if ((t & 63) == 0) nzs[t >> 6] = (bal != 0ull) ? 1 : 0;
        __syncthreads();
        if (t == 0) {
            *flag = (nzs[0] | nzs[1] | nzs[2] | nzs[3]) ? 0 : 1;  // 1 = int64 input
            *s1cnt = 0;
            *s2cnt = 0;
        }
    }
}

// ---------------- K1: persistent claim-based build ----------------
// phase 1: bin edge chunks (single edge read, LDS-staged entries);
// phase 2: Wc pack + x->bf16 units; phase 3: per-bucket CSR fill
// (gated on done==NCHUNK; deadlock-free: spin only when all chunks
// claimed -> claimants resident or retired).
__global__ __launch_bounds__(256) void build_kernel(
    const int* __restrict__ ei, const int* __restrict__ flag,
    int* __restrict__ bincnt, unsigned* __restrict__ bins,
    int* __restrict__ s1cnt, int* __restrict__ spill1,
    int* __restrict__ s2cnt, int* __restrict__ spill2,
    int* __restrict__ adj, int* __restrict__ cursor,
    const float* __restrict__ Wl, const float* __restrict__ Wr,
    unsigned short* __restrict__ Wc,
    const float4* __restrict__ x4, uint2* __restrict__ xb2, long total4,
    int* __restrict__ q, int E, int N, int NBUK, int NCHUNK, int NXBU) {
    __shared__ int hist[NBUK_MAX];
    __shared__ int rbase[NBUK_MAX];
    __shared__ unsigned ent[CHUNK];
    __shared__ unsigned short ebk[CHUNK];
    __shared__ int claim;
    const int t = threadIdx.x;
    const int is64 = *flag;
    int* binq = q + 0;
    int* xbq = q + 8;
    int* fillq = q + 16;
    int* done = q + 24;

    // ---------- phase 1: bin chunks ----------
    for (;;) {
        __syncthreads();
        if (t == 0) claim = atomicAdd(binq, 1);
        __syncthreads();
        const int c = claim;
        if (c >= NCHUNK) break;
        const long e0 = (long)c * CHUNK;
        const int cnt = (int)min((long)CHUNK, (long)E - e0);
        for (int i = t; i < NBUK; i += 256) hist[i] = 0;
        __syncthreads();
        // read edges ONCE; stage packed entry + bucket in LDS; histogram
        for (int i = t; i < cnt; i += 256) {
            long e = e0 + i;
            int src, dst;
            if (is64) {
                src = (int)((const long long*)ei)[e];
                dst = (int)((const long long*)ei)[(long)E + e];
            } else {
                src = ei[e];
                dst = ei[(long)E + e];
            }
            src = min(max(src, 0), N - 1);
            dst = min(max(dst, 0), N - 1);
            int bk = dst >> LOGB;
            ent[i] = ((unsigned)(dst & (LOCB - 1)) << 25) | (unsigned)src;
            ebk[i] = (unsigned short)bk;
            atomicAdd(&hist[bk], 1);
        }
        __syncthreads();
        // reserve contiguous ranges (padded global counters)
        for (int i = t; i < NBUK; i += 256) {
            int h = hist[i];
            rbase[i] = (h > 0) ? atomicAdd(&bincnt[i * BPAD], h) : 0;
            hist[i] = 0;  // reuse as bump counter
        }
        __syncthreads();
        // scatter from LDS
        for (int i = t; i < cnt; i += 256) {
            int bk = ebk[i];
            int slot = rbase[bk] + atomicAdd(&hist[bk], 1);
            if (slot < BCAP) {
                bins[(long)bk * BCAP + slot] = ent[i];
            } else {
                unsigned v = ent[i];
                int sp = atomicAdd(s1cnt, 1);
                if (sp < S1CAP) {
                    spill1[2 * sp] = (int)(v & 0x1FFFFFFu);
                    spill1[2 * sp + 1] = (bk << LOGB) | (int)(v >> 25);
                }
            }
        }
        // release: stores visible before done++
        __threadfence();
        __syncthreads();
        if (t == 0) atomicAdd(done, 1);
    }

    // ---------- phase 2: Wc pack (units [0,128)) + xb convert ----------
    for (;;) {
        __syncthreads();
        if (t == 0) claim = atomicAdd(xbq, 1);
        __syncthreads();
        const int c = claim;
        if (c >= 128 + NXBU) break;
        if (c < 128) {
            float w = (t < 128) ? Wl[c * 128 + t] : Wr[c * 128 + (t - 128)];
            Wc[c * 256 + t] = f2bf(w);
        } else {
            long g0 = (long)(c - 128) * (256 * USPAN);
#pragma unroll
            for (int u = 0; u < USPAN; ++u) {
                long gid = g0 + u * 256 + t;
                if (gid < total4) {
                    float4 v = x4[gid];
                    uint2 o;
                    o.x = (unsigned)f2bf(v.x) | ((unsigned)f2bf(v.y) << 16);
                    o.y = (unsigned)f2bf(v.z) | ((unsigned)f2bf(v.w) << 16);
                    xb2[gid] = o;
                }
            }
        }
    }

    // ---------- phase 3: per-bucket CSR fill (after all bin chunks) ----------
    if (t == 0) {
        while (atomicAdd(done, 0) < NCHUNK) __builtin_amdgcn_s_sleep(32);
    }
    __syncthreads();
    __threadfence();  // acquire
    int* cur = hist;  // reuse LDS
    for (;;) {
        __syncthreads();
        if (t == 0) claim = atomicAdd(fillq, 1);
        __syncthreads();
        const int bk = claim;
        if (bk >= NBUK) break;
        if (t < LOCB) cur[t] = 0;
        __syncthreads();
        const int cnt = min(bincnt[bk * BPAD], BCAP);
        const int nb = bk << LOGB;
        for (int i = t; i < cnt; i += 256) {
            unsigned v = bins[(long)bk * BCAP + i];
            int src = (int)(v & 0x1FFFFFFu);
            int ld = (int)(v >> 25);
            int slot = atomicAdd(&cur[ld], 1);
            if (slot < CAP) {
                adj[(long)(nb + ld) * CAP + slot] = src;
            } else {
                int sp = atomicAdd(s2cnt, 1);
                if (sp < S2CAP) {
                    spill2[2 * sp] = src;
                    spill2[2 * sp + 1] = nb + ld;
                }
            }
        }
        // re-insert this bucket's BCAP-overflow edges (normally zero)
        const int sc = min(*s1cnt, S1CAP);
        for (int i = t; i < sc; i += 256) {
            int dst = spill1[2 * i + 1];
            if ((dst >> LOGB) == bk) {
                int src = spill1[2 * i];
                int ld = dst & (LOCB - 1);
                int slot = atomicAdd(&cur[ld], 1);
                if (slot < CAP) {
                    adj[(long)dst * CAP + slot] = src;
                } else {
                    int sp = atomicAdd(s2cnt, 1);
                    if (sp < S2CAP) {
                        spill2[2 * sp] = src;
                        spill2[2 * sp + 1] = dst;
                    }
                }
            }
        }
        __syncthreads();
        if (t < LOCB && nb + t < N) cursor[nb + t] = cur[t];
    }
}

__device__ __forceinline__ void acc_row(float* acc, uint4 v) {
    acc[0] += __builtin_bit_cast(float, v.x << 16);
    acc[1] += __builtin_bit_cast(float, v.x & 0xFFFF0000u);
    acc[2] += __builtin_bit_cast(float, v.y << 16);
    acc[3] += __builtin_bit_cast(float, v.y & 0xFFFF0000u);
    acc[4] += __builtin_bit_cast(float, v.z << 16);
    acc[5] += __builtin_bit_cast(float, v.z & 0xFFFF0000u);
    acc[6] += __builtin_bit_cast(float, v.w << 16);
    acc[7] += __builtin_bit_cast(float, v.w & 0xFFFF0000u);
}

// src for edge e of this quad's node; e >= cq redirects to row 0 (L1-hot).
__device__ __forceinline__ int pick_src(int adjv, int adjv2, int e, int cq, int qd) {
    int ec = e & 31;
    int s = __shfl((ec < 16) ? adjv : adjv2, qd * 16 + (ec & 15));
    return (e < cq) ? s : 0;
}

// ---------------- K2: fused gather + MFMA GEMM, 16 nodes per block ----------------
__global__ __launch_bounds__(256) void gg_kernel(
    const unsigned int* __restrict__ xb, const int* __restrict__ cursor,
    const int* __restrict__ adj, const unsigned short* __restrict__ Wc,
    const float* __restrict__ bl, float* __restrict__ out, int N) {
    __shared__ __align__(16) unsigned short A[16 * 264];

    const int t = threadIdx.x;
    const int wv = t >> 6;
    const int lane = t & 63;
    const int n0 = blockIdx.x * 16;
    const int fq = lane & 15;   // position within quad
    const int qd = lane >> 4;   // quad id = which of the wave's 4 nodes

    const int n = n0 + wv * 4 + qd;
    const int nc = min(n, N - 1);

    // independent front-loads: degree, adjacency (2x), own rows (4x)
    const int deg = (n < N) ? cursor[n] : 0;
    int adjv = adj[(long)nc * CAP + fq];
    int adjv2 = adj[(long)nc * CAP + 16 + fq];

    unsigned xv[4];
#pragma unroll
    for (int q = 0; q < 4; ++q) {
        int nn = n0 + wv * 4 + q;
        xv[q] = (nn < N) ? xb[(long)nn * 64 + lane] : 0u;
    }

    // clamp stored srcs (entries beyond deg are uninitialized garbage)
    adjv = min(max(adjv, 0), N - 1);
    adjv2 = min(max(adjv2, 0), N - 1);

    const int cq = min(deg, CAP);
    int mx = max(cq, __shfl_xor(cq, 16));
    mx = max(mx, __shfl_xor(mx, 32));
    mx = (mx + 3) & ~3;  // pad to chunk of 4

    float acc[8] = {0.f, 0.f, 0.f, 0.f, 0.f, 0.f, 0.f, 0.f};
    uint4 va[4], vb[4];
    // prefetch chunk 0
#pragma unroll
    for (int j = 0; j < 4; ++j) {
        int s = pick_src(adjv, adjv2, j, cq, qd);
        va[j] = *(const uint4*)&xb[(long)s * 64 + fq * 4];
    }
    for (int base = 0; base < mx; base += 4) {
        // issue next chunk's 4 loads before consuming current chunk
#pragma unroll
        for (int j = 0; j < 4; ++j) {
            int s = pick_src(adjv, adjv2, base + 4 + j, cq, qd);
            vb[j] = *(const uint4*)&xb[(long)s * 64 + fq * 4];
        }
#pragma unroll
        for (int j = 0; j < 4; ++j) {
            if (base + j < cq) acc_row(acc, va[j]);
        }
#pragma unroll
        for (int j = 0; j < 4; ++j) va[j] = vb[j];
    }

    const float iv = 1.0f / (float)max(deg, 1);
    uint4 o;
    o.x = (unsigned)f2bf(acc[0] * iv) | ((unsigned)f2bf(acc[1] * iv) << 16);
    o.y = (unsigned)f2bf(acc[2] * iv) | ((unsigned)f2bf(acc[3] * iv) << 16);
    o.z = (unsigned)f2bf(acc[4] * iv) | ((unsigned)f2bf(acc[5] * iv) << 16);
    o.w = (unsigned)f2bf(acc[6] * iv) | ((unsigned)f2bf(acc[7] * iv) << 16);
    *(uint4*)&A[(wv * 4 + qd) * 264 + fq * 8] = o;
#pragma unroll
    for (int q = 0; q < 4; ++q)
        *(unsigned*)&A[(wv * 4 + q) * 264 + 128 + 2 * lane] = xv[q];
    __syncthreads();

    // phase 2: MFMA — wave w computes cols [w*32, w*32+32)
    const int l15 = lane & 15;
    const int quad = lane >> 4;
    f32x4 acc2[2];
    acc2[0] = (f32x4){0.f, 0.f, 0.f, 0.f};
    acc2[1] = (f32x4){0.f, 0.f, 0.f, 0.f};

#pragma unroll
    for (int kc = 0; kc < 8; ++kc) {
        const int k0 = kc * 32;
        bf16x8 af = *(const bf16x8*)&A[l15 * 264 + k0 + quad * 8];
#pragma unroll
        for (int nt = 0; nt < 2; ++nt) {
            int col = wv * 32 + nt * 16 + l15;
            bf16x8 bf = *(const bf16x8*)&Wc[col * 256 + k0 + quad * 8];
            acc2[nt] = __builtin_amdgcn_mfma_f32_16x16x32_bf16(af, bf, acc2[nt], 0, 0, 0);
        }
    }

    // epilogue: C/D layout col=lane&15, row=quad*4+reg
#pragma unroll
    for (int nt = 0; nt < 2; ++nt) {
        int col = wv * 32 + nt * 16 + l15;
        float bias = bl[col];
#pragma unroll
        for (int r = 0; r < 4; ++r) {
            int node = n0 + quad * 4 + r;
            if (node < N) out[(long)node * 128 + col] = acc2[nt][r] + bias;
        }
    }
}

// ---------------- K3: exact CAP-overflow fixup (normally ~0 iterations) ----------
__global__ __launch_bounds__(256) void spill2_kernel(
    const float* __restrict__ x, const float* __restrict__ Wl,
    const int* __restrict__ cursor, const int* __restrict__ s2cnt,
    const int* __restrict__ spill2, float* __restrict__ out) {
    const int wv = threadIdx.x >> 6;
    const int lane = threadIdx.x & 63;
    const int sc = min(*s2cnt, S2CAP);
    for (int i = blockIdx.x * 4 + wv; i < sc; i += gridDim.x * 4) {
        int src = spill2[2 * i];
        int dst = spill2[2 * i + 1];
        float inv = 1.0f / (float)max(cursor[dst], 1);
#pragma unroll
        for (int cc = 0; cc < 2; ++cc) {
            int c = lane + cc * 64;
            float s = 0.0f;
            for (int k = 0; k < 128; k += 4) {
                float4 w4 = *(const float4*)&Wl[c * 128 + k];
                float4 x4 = *(const float4*)&x[(long)src * 128 + k];
                s += w4.x * x4.x + w4.y * x4.y + w4.z * x4.z + w4.w * x4.w;
            }
            atomicAdd(&out[(long)dst * 128 + c], s * inv);
        }
    }
}

extern "C" void kernel_launch(void* const* d_in, const int* in_sizes, int n_in,
                              void* d_out, int out_size, void* d_ws, size_t ws_size,
                              hipStream_t stream) {
    const float* x = (const float*)d_in[0];
    const int* ei = (const int*)d_in[1];
    const float* Wl = (const float*)d_in[2];
    const float* bl = (const float*)d_in[3];
    const float* Wr = (const float*)d_in[4];
    float* out = (float*)d_out;

    const int N = in_sizes[0] / D_FEAT;  // 100000
    const int E = in_sizes[1] / 2;       // 1600000
    const int NBUK = (N + LOCB - 1) >> LOGB;     // 782 (<= NBUK_MAX)
    const int NCHUNK = (E + CHUNK - 1) / CHUNK;  // 391

    int* wsI = (int*)d_ws;
    int* flag = wsI;                          // 64
    int* cursor = flag + 64;                  // N (degree after fill)
    int* s1cnt = cursor + N;                  // 64
    int* spill1 = s1cnt + 64;                 // 2*S1CAP
    int* s2cnt = spill1 + 2 * S1CAP;          // 64
    int* spill2 = s2cnt + 64;                 // 2*S2CAP
    int* bincnt = spill2 + 2 * S2CAP;         // NBUK_MAX*BPAD
    int* q = bincnt + NBUK_MAX * BPAD;        // 64 (binq,xbq,fillq,done)
    unsigned* bins = (unsigned*)(q + 64);                         // NBUK*BCAP
    int* adj = (int*)(bins + (long)NBUK * BCAP);                  // N*CAP
    unsigned short* Wc = (unsigned short*)(adj + (long)N * CAP);  // 64KB
    unsigned int* xb = (unsigned int*)(Wc + 128 * 256);           // N*64 uints

    const long total4 = (long)N * 32;
    const int NXBU = (int)((total4 + 256 * USPAN - 1) / (256 * USPAN));

    tprep_kernel<<<8, 256, 0, stream>>>(ei, flag, s1cnt, s2cnt, bincnt, q);
    build_kernel<<<BUILD_BLOCKS, 256, 0, stream>>>(
        ei, flag, bincnt, bins, s1cnt, spill1, s2cnt, spill2, adj, cursor,
        Wl, Wr, Wc, (const float4*)x, (uint2*)xb, total4, q, E, N, NBUK,
        NCHUNK, NXBU);
    gg_kernel<<<(N + 15) / 16, 256, 0, stream>>>(xb, cursor, adj, Wc, bl, out, N);
    spill2_kernel<<<64, 256, 0, stream>>>(x, Wl, cursor, s2cnt, spill2, out);
}

// Round 9
// 243.914 us; speedup vs baseline: 2.2604x; 2.2604x over previous
//
#include <hip/hip_runtime.h>

#define D_FEAT 128
#define CAP 32
#define S1CAP (1 << 16)
#define S2CAP (1 << 16)
#define LOGB 7
#define LOCB 128
#define BCAP 2560
#define CHUNK 4096
#define NBUK_MAX 1024
#define BPAD 8

typedef short bf16x8 __attribute__((ext_vector_type(8)));
typedef float f32x4 __attribute__((ext_vector_type(4)));

__device__ __forceinline__ unsigned short f2bf(float f) {
    unsigned u = __builtin_bit_cast(unsigned, f);
    u += 0x7FFF + ((u >> 16) & 1);   // round-to-nearest-even
    return (unsigned short)(u >> 16);
}

// ws int layout: [flag:64][cursor:N][s1cnt:64][spill1:2*S1CAP][s2cnt:64]
// [spill2:2*S2CAP][bincnt:NBUK_MAX*BPAD][bins:NBUK*BCAP][adj:N*CAP]
// then Wc[128*256] bf16, xb[N*64] uint (bf16x2)

// ---------------- K0: tiny prep: detect i64 + zero counters (8 blocks) ----------
__global__ __launch_bounds__(256) void tprep_kernel(
    const int* __restrict__ ei, int* __restrict__ flag, int* __restrict__ s1cnt,
    int* __restrict__ s2cnt, int* __restrict__ bincnt) {
    const int b = blockIdx.x;
    const int t = threadIdx.x;
    for (int i = b * 256 + t; i < NBUK_MAX * BPAD; i += 8 * 256) bincnt[i] = 0;
    if (b == 0) {
        __shared__ int nzs[4];
        int nz = 0;
        for (int i = t; i < 4096; i += 256) nz |= (ei[2 * i + 1] != 0);
        unsigned long long bal = __ballot(nz);
        if ((t & 63) == 0) nzs[t >> 6] = (bal != 0ull) ? 1 : 0;
        __syncthreads();
        if (t == 0) {
            *flag = (nzs[0] | nzs[1] | nzs[2] | nzs[3]) ? 0 : 1;  // 1 = int64 input
            *s1cnt = 0;
            *s2cnt = 0;
        }
    }
}

// ---------------- K1: merged bin + Wc pack + x->bf16 (one launch) ----------------
// blocks [0, BINB): edge binning — single edge read, packed entries staged in
// LDS, then range-reserve + scatter; blocks [BINB, BINB+128): Wc pack; rest:
// xb conversion (streaming blocks fill the machine and hide bin latency).
__global__ __launch_bounds__(256) void bwx_kernel(
    const int* __restrict__ ei, const int* __restrict__ flag,
    int* __restrict__ bincnt, unsigned* __restrict__ bins,
    int* __restrict__ s1cnt, int* __restrict__ spill1, int E, int N, int NBUK,
    int BINB,
    const float* __restrict__ Wl, const float* __restrict__ Wr,
    unsigned short* __restrict__ Wc,
    const float4* __restrict__ x4, uint2* __restrict__ xb2, long total4) {
    const int b = blockIdx.x;
    const int t = threadIdx.x;

    if (b < BINB) {
        __shared__ int hist[NBUK_MAX];
        __shared__ int rbase[NBUK_MAX];
        __shared__ unsigned ent[CHUNK];
        __shared__ unsigned short ebk[CHUNK];
        const long e0 = (long)b * CHUNK;
        const int cnt = (int)min((long)CHUNK, (long)E - e0);
        const int is64 = *flag;

        for (int i = t; i < NBUK; i += 256) hist[i] = 0;
        __syncthreads();

        // phase A: read edges ONCE; stage packed entry + bucket; histogram
        for (int i = t; i < cnt; i += 256) {
            long e = e0 + i;
            int src, dst;
            if (is64) {
                src = (int)((const long long*)ei)[e];
                dst = (int)((const long long*)ei)[(long)E + e];
            } else {
                src = ei[e];
                dst = ei[(long)E + e];
            }
            src = min(max(src, 0), N - 1);
            dst = min(max(dst, 0), N - 1);
            int bk = dst >> LOGB;
            ent[i] = ((unsigned)(dst & (LOCB - 1)) << 25) | (unsigned)src;
            ebk[i] = (unsigned short)bk;
            atomicAdd(&hist[bk], 1);
        }
        __syncthreads();

        // phase B: reserve contiguous ranges (padded counters: 4/line not 32/line)
        for (int i = t; i < NBUK; i += 256) {
            int h = hist[i];
            rbase[i] = (h > 0) ? atomicAdd(&bincnt[i * BPAD], h) : 0;
            hist[i] = 0;  // reuse as bump counter
        }
        __syncthreads();

        // phase C: scatter from LDS
        for (int i = t; i < cnt; i += 256) {
            int bk = ebk[i];
            int slot = rbase[bk] + atomicAdd(&hist[bk], 1);
            if (slot < BCAP) {
                bins[(long)bk * BCAP + slot] = ent[i];
            } else {
                unsigned v = ent[i];
                int sp = atomicAdd(s1cnt, 1);
                if (sp < S1CAP) {
                    spill1[2 * sp] = (int)(v & 0x1FFFFFFu);
                    spill1[2 * sp + 1] = (bk << LOGB) | (int)(v >> 25);
                }
            }
        }
    } else if (b < BINB + 128) {
        int n = b - BINB;  // 0..127
        float w = (t < 128) ? Wl[n * 128 + t] : Wr[n * 128 + (t - 128)];
        Wc[n * 256 + t] = f2bf(w);
    } else {
        long gid = (long)(b - BINB - 128) * 256 + t;
        if (gid < total4) {
            float4 v = x4[gid];
            uint2 o;
            o.x = (unsigned)f2bf(v.x) | ((unsigned)f2bf(v.y) << 16);
            o.y = (unsigned)f2bf(v.z) | ((unsigned)f2bf(v.w) << 16);
            xb2[gid] = o;
        }
    }
}

// ---------------- K2: per-bucket CSR fill — LDS adj image + coalesced writeout --
__global__ __launch_bounds__(256) void fill2_kernel(
    const unsigned* __restrict__ bins, const int* __restrict__ bincnt,
    int* __restrict__ adj, int* __restrict__ cursor,
    const int* __restrict__ s1cnt, const int* __restrict__ spill1,
    int* __restrict__ s2cnt, int* __restrict__ spill2, int N) {
    __shared__ int cur[LOCB];
    __shared__ __align__(16) int adjimg[LOCB * CAP];  // 16KB bucket adj image
    const int bk = blockIdx.x;
    const int t = threadIdx.x;
    if (t < LOCB) cur[t] = 0;
    __syncthreads();
    const int cnt = min(bincnt[bk * BPAD], BCAP);
    const int nb = bk << LOGB;
    for (int i = t; i < cnt; i += 256) {
        unsigned v = bins[(long)bk * BCAP + i];
        int src = (int)(v & 0x1FFFFFFu);
        int ld = (int)(v >> 25);
        int slot = atomicAdd(&cur[ld], 1);
        if (slot < CAP) {
            adjimg[ld * CAP + slot] = src;
        } else {
            int sp = atomicAdd(s2cnt, 1);
            if (sp < S2CAP) {
                spill2[2 * sp] = src;
                spill2[2 * sp + 1] = nb + ld;
            }
        }
    }
    // re-insert this bucket's BCAP-overflow edges (normally zero entries)
    const int sc = min(*s1cnt, S1CAP);
    for (int i = t; i < sc; i += 256) {
        int dst = spill1[2 * i + 1];
        if ((dst >> LOGB) == bk) {
            int src = spill1[2 * i];
            int ld = dst & (LOCB - 1);
            int slot = atomicAdd(&cur[ld], 1);
            if (slot < CAP) {
                adjimg[ld * CAP + slot] = src;
            } else {
                int sp = atomicAdd(s2cnt, 1);
                if (sp < S2CAP) {
                    spill2[2 * sp] = src;
                    spill2[2 * sp + 1] = dst;
                }
            }
        }
    }
    __syncthreads();
    // coalesced writeout: this bucket's adj slice is contiguous (node-major*CAP)
    const int lim = min(LOCB, N - nb);          // valid nodes in bucket
    const int nvec = lim * CAP / 4;             // uint4 count (CAP=32 -> /4 exact)
    uint4* dstp = (uint4*)&adj[(long)nb * CAP];
    const uint4* srcp = (const uint4*)adjimg;
    for (int i = t; i < nvec; i += 256) dstp[i] = srcp[i];
    if (t < LOCB && nb + t < N) cursor[nb + t] = cur[t];
}

__device__ __forceinline__ void acc_row(float* acc, uint4 v) {
    acc[0] += __builtin_bit_cast(float, v.x << 16);
    acc[1] += __builtin_bit_cast(float, v.x & 0xFFFF0000u);
    acc[2] += __builtin_bit_cast(float, v.y << 16);
    acc[3] += __builtin_bit_cast(float, v.y & 0xFFFF0000u);
    acc[4] += __builtin_bit_cast(float, v.z << 16);
    acc[5] += __builtin_bit_cast(float, v.z & 0xFFFF0000u);
    acc[6] += __builtin_bit_cast(float, v.w << 16);
    acc[7] += __builtin_bit_cast(float, v.w & 0xFFFF0000u);
}

// src for edge e of this quad's node; e >= cq redirects to row 0 (L1-hot).
__device__ __forceinline__ int pick_src(int adjv, int adjv2, int e, int cq, int qd) {
    int ec = e & 31;
    int s = __shfl((ec < 16) ? adjv : adjv2, qd * 16 + (ec & 15));
    return (e < cq) ? s : 0;
}

// ---------------- K3: fused gather + MFMA GEMM, 16 nodes per block ----------------
__global__ __launch_bounds__(256) void gg_kernel(
    const unsigned int* __restrict__ xb, const int* __restrict__ cursor,
    const int* __restrict__ adj, const unsigned short* __restrict__ Wc,
    const float* __restrict__ bl, float* __restrict__ out, int N) {
    __shared__ __align__(16) unsigned short A[16 * 264];

    const int t = threadIdx.x;
    const int wv = t >> 6;
    const int lane = t & 63;
    const int n0 = blockIdx.x * 16;
    const int fq = lane & 15;   // position within quad
    const int qd = lane >> 4;   // quad id = which of the wave's 4 nodes

    const int n = n0 + wv * 4 + qd;
    const int nc = min(n, N - 1);

    // independent front-loads: degree, adjacency (2x), own rows (4x)
    const int deg = (n < N) ? cursor[n] : 0;
    int adjv = adj[(long)nc * CAP + fq];
    int adjv2 = adj[(long)nc * CAP + 16 + fq];

    unsigned xv[4];
#pragma unroll
    for (int q = 0; q < 4; ++q) {
        int nn = n0 + wv * 4 + q;
        xv[q] = (nn < N) ? xb[(long)nn * 64 + lane] : 0u;
    }

    // clamp stored srcs (entries beyond deg are uninitialized garbage)
    adjv = min(max(adjv, 0), N - 1);
    adjv2 = min(max(adjv2, 0), N - 1);

    const int cq = min(deg, CAP);
    int mx = max(cq, __shfl_xor(cq, 16));
    mx = max(mx, __shfl_xor(mx, 32));
    mx = (mx + 3) & ~3;  // pad to chunk of 4

    float acc[8] = {0.f, 0.f, 0.f, 0.f, 0.f, 0.f, 0.f, 0.f};
    uint4 va[4], vb[4];
    // prefetch chunk 0
#pragma unroll
    for (int j = 0; j < 4; ++j) {
        int s = pick_src(adjv, adjv2, j, cq, qd);
        va[j] = *(const uint4*)&xb[(long)s * 64 + fq * 4];
    }
    for (int base = 0; base < mx; base += 4) {
        // issue next chunk's 4 loads before consuming current chunk
#pragma unroll
        for (int j = 0; j < 4; ++j) {
            int s = pick_src(adjv, adjv2, base + 4 + j, cq, qd);
            vb[j] = *(const uint4*)&xb[(long)s * 64 + fq * 4];
        }
#pragma unroll
        for (int j = 0; j < 4; ++j) {
            if (base + j < cq) acc_row(acc, va[j]);
        }
#pragma unroll
        for (int j = 0; j < 4; ++j) va[j] = vb[j];
    }

    const float iv = 1.0f / (float)max(deg, 1);
    uint4 o;
    o.x = (unsigned)f2bf(acc[0] * iv) | ((unsigned)f2bf(acc[1] * iv) << 16);
    o.y = (unsigned)f2bf(acc[2] * iv) | ((unsigned)f2bf(acc[3] * iv) << 16);
    o.z = (unsigned)f2bf(acc[4] * iv) | ((unsigned)f2bf(acc[5] * iv) << 16);
    o.w = (unsigned)f2bf(acc[6] * iv) | ((unsigned)f2bf(acc[7] * iv) << 16);
    *(uint4*)&A[(wv * 4 + qd) * 264 + fq * 8] = o;
#pragma unroll
    for (int q = 0; q < 4; ++q)
        *(unsigned*)&A[(wv * 4 + q) * 264 + 128 + 2 * lane] = xv[q];
    __syncthreads();

    // phase 2: MFMA — wave w computes cols [w*32, w*32+32)
    const int l15 = lane & 15;
    const int quad = lane >> 4;
    f32x4 acc2[2];
    acc2[0] = (f32x4){0.f, 0.f, 0.f, 0.f};
    acc2[1] = (f32x4){0.f, 0.f, 0.f, 0.f};

#pragma unroll
    for (int kc = 0; kc < 8; ++kc) {
        const int k0 = kc * 32;
        bf16x8 af = *(const bf16x8*)&A[l15 * 264 + k0 + quad * 8];
#pragma unroll
        for (int nt = 0; nt < 2; ++nt) {
            int col = wv * 32 + nt * 16 + l15;
            bf16x8 bf = *(const bf16x8*)&Wc[col * 256 + k0 + quad * 8];
            acc2[nt] = __builtin_amdgcn_mfma_f32_16x16x32_bf16(af, bf, acc2[nt], 0, 0, 0);
        }
    }

    // epilogue: C/D layout col=lane&15, row=quad*4+reg
#pragma unroll
    for (int nt = 0; nt < 2; ++nt) {
        int col = wv * 32 + nt * 16 + l15;
        float bias = bl[col];
#pragma unroll
        for (int r = 0; r < 4; ++r) {
            int node = n0 + quad * 4 + r;
            if (node < N) out[(long)node * 128 + col] = acc2[nt][r] + bias;
        }
    }
}

// ---------------- K4: exact CAP-overflow fixup (normally ~0 iterations) ----------
__global__ __launch_bounds__(256) void spill2_kernel(
    const float* __restrict__ x, const float* __restrict__ Wl,
    const int* __restrict__ cursor, const int* __restrict__ s2cnt,
    const int* __restrict__ spill2, float* __restrict__ out) {
    const int wv = threadIdx.x >> 6;
    const int lane = threadIdx.x & 63;
    const int sc = min(*s2cnt, S2CAP);
    for (int i = blockIdx.x * 4 + wv; i < sc; i += gridDim.x * 4) {
        int src = spill2[2 * i];
        int dst = spill2[2 * i + 1];
        float inv = 1.0f / (float)max(cursor[dst], 1);
#pragma unroll
        for (int cc = 0; cc < 2; ++cc) {
            int c = lane + cc * 64;
            float s = 0.0f;
            for (int k = 0; k < 128; k += 4) {
                float4 w4 = *(const float4*)&Wl[c * 128 + k];
                float4 x4 = *(const float4*)&x[(long)src * 128 + k];
                s += w4.x * x4.x + w4.y * x4.y + w4.z * x4.z + w4.w * x4.w;
            }
            atomicAdd(&out[(long)dst * 128 + c], s * inv);
        }
    }
}

extern "C" void kernel_launch(void* const* d_in, const int* in_sizes, int n_in,
                              void* d_out, int out_size, void* d_ws, size_t ws_size,
                              hipStream_t stream) {
    const float* x = (const float*)d_in[0];
    const int* ei = (const int*)d_in[1];
    const float* Wl = (const float*)d_in[2];
    const float* bl = (const float*)d_in[3];
    const float* Wr = (const float*)d_in[4];
    float* out = (float*)d_out;

    const int N = in_sizes[0] / D_FEAT;  // 100000
    const int E = in_sizes[1] / 2;       // 1600000
    const int NBUK = (N + LOCB - 1) >> LOGB;  // 782 (<= NBUK_MAX)
    const int BINB = (E + CHUNK - 1) / CHUNK; // 391

    int* wsI = (int*)d_ws;
    int* flag = wsI;                          // 64
    int* cursor = flag + 64;                  // N (degree after fill)
    int* s1cnt = cursor + N;                  // 64
    int* spill1 = s1cnt + 64;                 // 2*S1CAP
    int* s2cnt = spill1 + 2 * S1CAP;          // 64
    int* spill2 = s2cnt + 64;                 // 2*S2CAP
    int* bincnt = spill2 + 2 * S2CAP;         // NBUK_MAX*BPAD
    unsigned* bins = (unsigned*)(bincnt + NBUK_MAX * BPAD);       // NBUK*BCAP
    int* adj = (int*)(bins + (long)NBUK * BCAP);                  // N*CAP
    unsigned short* Wc = (unsigned short*)(adj + (long)N * CAP);  // 64KB
    unsigned int* xb = (unsigned int*)(Wc + 128 * 256);           // N*64 uints

    const long total4 = (long)N * 32;
    const int XBB = (int)((total4 + 255) / 256);

    tprep_kernel<<<8, 256, 0, stream>>>(ei, flag, s1cnt, s2cnt, bincnt);
    bwx_kernel<<<BINB + 128 + XBB, 256, 0, stream>>>(
        ei, flag, bincnt, bins, s1cnt, spill1, E, N, NBUK, BINB, Wl, Wr, Wc,
        (const float4*)x, (uint2*)xb, total4);
    fill2_kernel<<<NBUK, 256, 0, stream>>>(bins, bincnt, adj, cursor, s1cnt, spill1,
                                           s2cnt, spill2, N);
    gg_kernel<<<(N + 15) / 16, 256, 0, stream>>>(xb, cursor, adj, Wc, bl, out, N);
    spill2_kernel<<<64, 256, 0, stream>>>(x, Wl, cursor, s2cnt, spill2, out);
}